// Round 1
// baseline (472.735 us; speedup 1.0000x reference)
//
#include <hip/hip_runtime.h>
#include <math.h>

// Problem constants
#define N_CELLS 50000
#define C_CLS   30
#define G_GENES 1000
#define E_EDGES 800000
#define KPAD    1024
#define NREP    4

typedef __attribute__((ext_vector_type(8))) short bf16x8;
typedef __attribute__((ext_vector_type(4))) float f32x4;

// fp32 -> bf16 (RNE), raw ushort payload
__device__ __forceinline__ unsigned f2bf_u(float f) {
    unsigned u = __float_as_uint(f);
    return (u + 0x7fffu + ((u >> 16) & 1u)) >> 16;
}
__device__ __forceinline__ unsigned pack2(float lo, float hi) {
    return f2bf_u(lo) | (f2bf_u(hi) << 16);
}
__device__ __forceinline__ float bf2f(unsigned short u) {
    return __uint_as_float(((unsigned)u) << 16);
}

__device__ __forceinline__ float lrelu02(float v) { return v > 0.f ? v : 0.2f * v; }

// dot of 8 bf16 pairs packed in int4s
__device__ __forceinline__ float dp4(int4 a, int4 b) {
    const unsigned* ua = (const unsigned*)&a;
    const unsigned* ub = (const unsigned*)&b;
    float s = 0.f;
#pragma unroll
    for (int i = 0; i < 4; i++) {
        float al = __uint_as_float(ua[i] << 16);
        float ah = __uint_as_float(ua[i] & 0xffff0000u);
        float bl = __uint_as_float(ub[i] << 16);
        float bh = __uint_as_float(ub[i] & 0xffff0000u);
        s += al * bl + ah * bh;
    }
    return s;
}

// ---------------------------------------------------------------------------
// K0: pack CoefB bf16 [80][1024] + Dvec[30]; zero dn4 accumulators + out[0..1].
// ---------------------------------------------------------------------------
__global__ void prep_kernel(const float* __restrict__ Mu, const float* __restrict__ Var,
                            const float* __restrict__ Wl, const float* __restrict__ Wr,
                            unsigned short* __restrict__ CoefB, float* __restrict__ Dvec,
                            float* __restrict__ dn4, float* __restrict__ out) {
    const int r = blockIdx.x;
    const int t = threadIdx.x;
    __shared__ float red[256];
    float dacc = 0.f;
    for (int g = t; g < KPAD; g += 256) {
        float v = 0.f;
        if (g < G_GENES) {
            if (r < 30) {
                float iv = 1.0f / Var[r * G_GENES + g];
                float mu = Mu[r * G_GENES + g];
                v = iv;
                dacc += mu * mu * iv;
            } else if (r >= 32) {
                int i = r - 32;
                if (i < 30)      v = Mu[i * G_GENES + g] / Var[i * G_GENES + g];
                else if (i < 38) v = Wl[(i - 30) * G_GENES + g];
                else if (i < 46) v = Wr[(i - 38) * G_GENES + g];
            }
        }
        CoefB[r * KPAD + g] = (unsigned short)f2bf_u(v);
    }
    // zero the interleaved (denom,numer) replicated accumulators: NREP*N*2 floats
    for (int i = blockIdx.x * 256 + t; i < N_CELLS * NREP * 2; i += 80 * 256) dn4[i] = 0.f;
    if (r == 31 && t < 2) out[t] = 0.f;

    if (r < 30) {
        red[t] = dacc;
        __syncthreads();
        for (int s = 128; s > 0; s >>= 1) {
            if (t < s) red[t] += red[t + s];
            __syncthreads();
        }
        if (t == 0) Dvec[r] = red[0];
    }
}

// ---------------------------------------------------------------------------
// K1: MFMA row kernel — barrier-free.
// 64 rows/block, 4 independent waves; wave w owns rows w*16..w*16+15.
// B-fragments are read DIRECTLY from global CoefB (160 KB, L1/L2-resident):
// no LDS, no __syncthreads -> the X prefetch stays in flight across
// iterations and the compiler is free to software-pipeline on vmcnt alone.
// ---------------------------------------------------------------------------
__global__ __launch_bounds__(256, 3) void main_rows_kernel(
    const float* __restrict__ X, const float* __restrict__ W,
    const float* __restrict__ S, const float* __restrict__ bl,
    const float* __restrict__ br, const unsigned short* __restrict__ CoefB,
    const float* __restrict__ Dvec,
    float* __restrict__ out,          // [0]=ll, [1]=ce, [2..] = P row-major
    unsigned short* __restrict__ Pb, unsigned short* __restrict__ Lb,
    float* __restrict__ xl, float* __restrict__ xr)
{
    const int t    = threadIdx.x;
    const int w    = t >> 6;
    const int l    = t & 63;
    const int l15  = l & 15;
    const int quad = l >> 4;
    const int k0q  = quad * 8;
    const int wavebase = blockIdx.x * 64 + w * 16;
    if (wavebase >= N_CELLS) return;     // wave-uniform (N%16==0), no barriers anywhere
    const float* __restrict__ xrow = X + (size_t)(wavebase + l15) * G_GENES;
    const unsigned short* __restrict__ cb = CoefB + (size_t)l15 * KPAD + k0q;

    f32x4 acc[5];
#pragma unroll
    for (int i = 0; i < 5; i++) acc[i] = (f32x4){0.f, 0.f, 0.f, 0.f};

    // prefetch K-tile 0 (always in-bounds: k <= 63+7 < 1000)
    float4 c0a = *(const float4*)&xrow[k0q];
    float4 c0b = *(const float4*)&xrow[k0q + 4];
    float4 c1a = *(const float4*)&xrow[32 + k0q];
    float4 c1b = *(const float4*)&xrow[32 + k0q + 4];

#pragma unroll 2
    for (int kt = 0; kt < KPAD; kt += 64) {
        // issue next tile's X loads (consumed next iteration)
        float4 n0a = make_float4(0.f, 0.f, 0.f, 0.f), n0b = n0a, n1a = n0a, n1b = n0a;
        const int ktn = kt + 64;
        if (ktn < KPAD) {
            const int ka = ktn + k0q;          // ka+7 <= 991 always
            n0a = *(const float4*)&xrow[ka];
            n0b = *(const float4*)&xrow[ka + 4];
            const int kb = ktn + 32 + k0q;
            if (kb < G_GENES) {                // kb can reach 1016
                n1a = *(const float4*)&xrow[kb];
                n1b = *(const float4*)&xrow[kb + 4];
            }
        }

        // ---- pack + MFMA on current regs; B direct from global (L1/L2 hit) ----
        union { unsigned u[4]; bf16x8 v; } ua, u2;
        // ks = 0
        ua.u[0] = pack2(c0a.x, c0a.y); ua.u[1] = pack2(c0a.z, c0a.w);
        ua.u[2] = pack2(c0b.x, c0b.y); ua.u[3] = pack2(c0b.z, c0b.w);
        u2.u[0] = pack2(c0a.x * c0a.x, c0a.y * c0a.y);
        u2.u[1] = pack2(c0a.z * c0a.z, c0a.w * c0a.w);
        u2.u[2] = pack2(c0b.x * c0b.x, c0b.y * c0b.y);
        u2.u[3] = pack2(c0b.z * c0b.z, c0b.w * c0b.w);
#pragma unroll
        for (int nt = 0; nt < 5; nt++) {
            bf16x8 b = *(const bf16x8*)&cb[(size_t)nt * 16 * KPAD + kt];
            acc[nt] = __builtin_amdgcn_mfma_f32_16x16x32_bf16(
                nt < 2 ? u2.v : ua.v, b, acc[nt], 0, 0, 0);
        }
        // ks = 1
        ua.u[0] = pack2(c1a.x, c1a.y); ua.u[1] = pack2(c1a.z, c1a.w);
        ua.u[2] = pack2(c1b.x, c1b.y); ua.u[3] = pack2(c1b.z, c1b.w);
        u2.u[0] = pack2(c1a.x * c1a.x, c1a.y * c1a.y);
        u2.u[1] = pack2(c1a.z * c1a.z, c1a.w * c1a.w);
        u2.u[2] = pack2(c1b.x * c1b.x, c1b.y * c1b.y);
        u2.u[3] = pack2(c1b.z * c1b.z, c1b.w * c1b.w);
#pragma unroll
        for (int nt = 0; nt < 5; nt++) {
            bf16x8 b = *(const bf16x8*)&cb[(size_t)nt * 16 * KPAD + kt + 32];
            acc[nt] = __builtin_amdgcn_mfma_f32_16x16x32_bf16(
                nt < 2 ? u2.v : ua.v, b, acc[nt], 0, 0, 0);
        }

        c0a = n0a; c0b = n0b; c1a = n1a; c1b = n1b;
    }

    // Epilogue (per wave). acc[nt][reg]: packed col = nt*16+l15, row = quad*4+reg.
    const int rbase = wavebase + quad * 4;
    const bool c2ok = (l15 < 14);
    const float d0 = Dvec[l15];
    const float d1 = c2ok ? Dvec[16 + l15] : 0.f;
    float llacc = 0.f;
#pragma unroll
    for (int r = 0; r < 4; r++) {
        const int row = rbase + r;
        float w0 = W[(size_t)row * 30 + l15];
        float w1 = c2ok ? W[(size_t)row * 30 + 16 + l15] : -1e30f;
        float m = fmaxf(w0, w1);
#pragma unroll
        for (int mm = 1; mm < 16; mm <<= 1) m = fmaxf(m, __shfl_xor(m, mm, 64));
        float e0 = __expf(w0 - m);
        float e1 = c2ok ? __expf(w1 - m) : 0.f;
        float s = e0 + e1;
#pragma unroll
        for (int mm = 1; mm < 16; mm <<= 1) s += __shfl_xor(s, mm, 64);
        float inv = 1.0f / s;
        float p0 = e0 * inv, p1 = e1 * inv;
        float Sn = S[row], Sn2 = Sn * Sn;
        float F0 = -0.5f * (acc[0][r] - 2.0f * Sn * acc[2][r] + Sn2 * d0);
        float F1 = -0.5f * (acc[1][r] - 2.0f * Sn * acc[3][r] + Sn2 * d1);
        float lp = p0 * F0 + (c2ok ? p1 * F1 : 0.f);
#pragma unroll
        for (int mm = 1; mm < 16; mm <<= 1) lp += __shfl_xor(lp, mm, 64);
        llacc += lp;

        out[2 + (size_t)row * 30 + l15] = p0;
        float lg0 = __logf(p0 + 1e-8f);
        Pb[(size_t)row * 32 + l15] = (unsigned short)f2bf_u(p0);
        Lb[(size_t)row * 32 + l15] = (unsigned short)f2bf_u(lg0);
        if (c2ok) {
            out[2 + (size_t)row * 30 + 16 + l15] = p1;
            float lg1 = __logf(p1 + 1e-8f);
            Pb[(size_t)row * 32 + 16 + l15] = (unsigned short)f2bf_u(p1);
            Lb[(size_t)row * 32 + 16 + l15] = (unsigned short)f2bf_u(lg1);
        } else {
            Pb[(size_t)row * 32 + 16 + l15] = 0;
            Lb[(size_t)row * 32 + 16 + l15] = 0;
        }
        if (l15 >= 14)                xl[(size_t)row * 8 + (l15 - 14)] = acc[3][r] + bl[l15 - 14];
        else if (l15 < 6)             xl[(size_t)row * 8 + (l15 + 2)]  = acc[4][r] + bl[l15 + 2];
        if (l15 >= 6 && l15 < 14)     xr[(size_t)row * 8 + (l15 - 6)]  = acc[4][r] + br[l15 - 6];
    }
    llacc += __shfl_xor(llacc, 16, 64);
    llacc += __shfl_xor(llacc, 32, 64);
    if (l == 0) atomicAdd(&out[0], llacc * (1.0f / N_CELLS));
}

// ---------------------------------------------------------------------------
// K2: SINGLE edge pass. p = exp(e) (no max-subtraction: |e| ~ O(10)).
// dot = P[src].logP[dst] is independent of the softmax denominator, so
// accumulate the pair (p, p*dot) per destination and divide at the end:
//   ce = -sum_dst numer[dst]/denom[dst] / N.
// (p, p*dot) go to the SAME cache line (interleaved layout), 4 replicas
// (blockIdx&3) to cut line contention. Removes the entire second edge pass.
// ---------------------------------------------------------------------------
__global__ __launch_bounds__(256) void edge_pass(
    const int* __restrict__ ei, const float* __restrict__ xl,
    const float* __restrict__ xr, const float* __restrict__ att,
    const unsigned short* __restrict__ Pb, const unsigned short* __restrict__ Lb,
    float* __restrict__ dn4) {
    int e = blockIdx.x * 256 + threadIdx.x;
    if (e >= E_EDGES) return;
    int src = ei[e];
    int dst = ei[E_EDGES + e];
    const float4* lp = (const float4*)&xl[(size_t)src * 8];
    const float4* rp = (const float4*)&xr[(size_t)dst * 8];
    float4 l0 = lp[0], l1 = lp[1];
    float4 r0 = rp[0], r1 = rp[1];
    float ev = 0.f;
    ev += lrelu02(l0.x + r0.x) * att[0];
    ev += lrelu02(l0.y + r0.y) * att[1];
    ev += lrelu02(l0.z + r0.z) * att[2];
    ev += lrelu02(l0.w + r0.w) * att[3];
    ev += lrelu02(l1.x + r1.x) * att[4];
    ev += lrelu02(l1.y + r1.y) * att[5];
    ev += lrelu02(l1.z + r1.z) * att[6];
    ev += lrelu02(l1.w + r1.w) * att[7];
    float p = __expf(ev);

    const int4* ps = (const int4*)&Pb[(size_t)src * 32];
    const int4* ld = (const int4*)&Lb[(size_t)dst * 32];
    int4 a0 = ps[0], a1 = ps[1], a2 = ps[2], a3 = ps[3];
    int4 b0 = ld[0], b1 = ld[1], b2 = ld[2], b3 = ld[3];
    float dot = dp4(a0, b0) + dp4(a1, b1) + dp4(a2, b2) + dp4(a3, b3);

    float* base = &dn4[((size_t)(blockIdx.x & (NREP - 1)) * N_CELLS + dst) * 2];
    atomicAdd(base, p);
    atomicAdd(base + 1, p * dot);
}

// ---------------------------------------------------------------------------
// K3: finalize — fold replicas, ce = -sum numer/denom / N
// ---------------------------------------------------------------------------
__global__ __launch_bounds__(256) void finalize_kernel(const float* __restrict__ dn4,
                                                       float* __restrict__ out) {
    const int t = threadIdx.x;
    const int i = blockIdx.x * 256 + t;
    float c = 0.f;
    if (i < N_CELLS) {
        float d  = (dn4[(size_t)i * 2]     + dn4[((size_t)N_CELLS + i) * 2]) +
                   (dn4[((size_t)2 * N_CELLS + i) * 2] + dn4[((size_t)3 * N_CELLS + i) * 2]);
        float nm = (dn4[(size_t)i * 2 + 1] + dn4[((size_t)N_CELLS + i) * 2 + 1]) +
                   (dn4[((size_t)2 * N_CELLS + i) * 2 + 1] + dn4[((size_t)3 * N_CELLS + i) * 2 + 1]);
        c = nm / (d + 1e-16f);
    }
#pragma unroll
    for (int m = 1; m < 64; m <<= 1) c += __shfl_xor(c, m, 64);
    __shared__ float wsum[4];
    if ((t & 63) == 0) wsum[t >> 6] = c;
    __syncthreads();
    if (t == 0)
        atomicAdd(&out[1], -(wsum[0] + wsum[1] + wsum[2] + wsum[3]) * (1.0f / N_CELLS));
}

// ---------------------------------------------------------------------------
// launch
// ---------------------------------------------------------------------------
extern "C" void kernel_launch(void* const* d_in, const int* in_sizes, int n_in,
                              void* d_out, int out_size, void* d_ws, size_t ws_size,
                              hipStream_t stream) {
    const float* X   = (const float*)d_in[0];
    const float* Mu  = (const float*)d_in[1];
    const float* Var = (const float*)d_in[2];
    const int*   ei  = (const int*)d_in[3];
    const float* W   = (const float*)d_in[4];
    const float* S   = (const float*)d_in[5];
    const float* Wl  = (const float*)d_in[6];
    const float* bl  = (const float*)d_in[7];
    const float* Wr  = (const float*)d_in[8];
    const float* br  = (const float*)d_in[9];
    const float* att = (const float*)d_in[10];

    float* out = (float*)d_out;

    // ws layout (float offsets), total 2,840,992 fl = 11.36 MB
    float* wsf = (float*)d_ws;
    unsigned short* CoefB  = (unsigned short*)wsf;             // 80*1024 us = 40960 fl
    float* Dvec            = wsf + 40960;                      // 32
    unsigned short* Pb     = (unsigned short*)(wsf + 40992);   // N*32 us = 800000 fl
    unsigned short* Lb     = (unsigned short*)(wsf + 840992);  // N*32 us
    float* xl              = wsf + 1640992;                    // N*8
    float* xr              = wsf + 2040992;                    // N*8
    float* dn4             = wsf + 2440992;                    // NREP*N*2 = 400000

    prep_kernel<<<80, 256, 0, stream>>>(Mu, Var, Wl, Wr, CoefB, Dvec, dn4, out);
    main_rows_kernel<<<(N_CELLS + 63) / 64, 256, 0, stream>>>(
        X, W, S, bl, br, CoefB, Dvec, out, Pb, Lb, xl, xr);
    edge_pass<<<(E_EDGES + 255) / 256, 256, 0, stream>>>(ei, xl, xr, att, Pb, Lb, dn4);
    finalize_kernel<<<(N_CELLS + 255) / 256, 256, 0, stream>>>(dn4, out);
}

// Round 2
// 443.622 us; speedup vs baseline: 1.0656x; 1.0656x over previous
//
#include <hip/hip_runtime.h>
#include <hip/hip_bf16.h>
#include <math.h>

// Problem constants
#define N_CELLS 50000
#define C_CLS   30
#define G_GENES 1000
#define E_EDGES 800000
#define KPAD    1024
#define NREP    4

typedef __attribute__((ext_vector_type(8))) short bf16x8;
typedef __attribute__((ext_vector_type(4))) float f32x4;

// fp32 -> bf16 (RNE), raw ushort payload (bit-twiddle; used in prep/epilogue)
__device__ __forceinline__ unsigned f2bf_u(float f) {
    unsigned u = __float_as_uint(f);
    return (u + 0x7fffu + ((u >> 16) & 1u)) >> 16;
}
// packed 2x f32->bf16 via v_cvt_pk_bf16_f32 (compiler-generated, RNE)
__device__ __forceinline__ unsigned pack2(float lo, float hi) {
    union { __hip_bfloat162 h; unsigned u; } cv;
    cv.h = __float22bfloat162_rn(make_float2(lo, hi));
    return cv.u;
}
__device__ __forceinline__ float bf2f(unsigned short u) {
    return __uint_as_float(((unsigned)u) << 16);
}

__device__ __forceinline__ float lrelu02(float v) { return v > 0.f ? v : 0.2f * v; }

// dot of 8 bf16 pairs packed in one int4
__device__ __forceinline__ float dp4(int4 a, int4 b) {
    const unsigned* ua = (const unsigned*)&a;
    const unsigned* ub = (const unsigned*)&b;
    float s = 0.f;
#pragma unroll
    for (int i = 0; i < 4; i++) {
        float al = __uint_as_float(ua[i] << 16);
        float ah = __uint_as_float(ua[i] & 0xffff0000u);
        float bl = __uint_as_float(ub[i] << 16);
        float bh = __uint_as_float(ub[i] & 0xffff0000u);
        s += al * bl + ah * bh;
    }
    return s;
}

// ---------------------------------------------------------------------------
// K0: pack CoefB bf16 [80][1024] + Dvec[30]; zero dn4 accumulators + out[0..1].
// ---------------------------------------------------------------------------
__global__ void prep_kernel(const float* __restrict__ Mu, const float* __restrict__ Var,
                            const float* __restrict__ Wl, const float* __restrict__ Wr,
                            unsigned short* __restrict__ CoefB, float* __restrict__ Dvec,
                            float* __restrict__ dn4, float* __restrict__ out) {
    const int r = blockIdx.x;
    const int t = threadIdx.x;
    __shared__ float red[256];
    float dacc = 0.f;
    for (int g = t; g < KPAD; g += 256) {
        float v = 0.f;
        if (g < G_GENES) {
            if (r < 30) {
                float iv = 1.0f / Var[r * G_GENES + g];
                float mu = Mu[r * G_GENES + g];
                v = iv;
                dacc += mu * mu * iv;
            } else if (r >= 32) {
                int i = r - 32;
                if (i < 30)      v = Mu[i * G_GENES + g] / Var[i * G_GENES + g];
                else if (i < 38) v = Wl[(i - 30) * G_GENES + g];
                else if (i < 46) v = Wr[(i - 38) * G_GENES + g];
            }
        }
        CoefB[r * KPAD + g] = (unsigned short)f2bf_u(v);
    }
    // zero the interleaved (denom,numer) replicated accumulators: NREP*N*2 floats
    for (int i = blockIdx.x * 256 + t; i < N_CELLS * NREP * 2; i += 80 * 256) dn4[i] = 0.f;
    if (r == 31 && t < 2) out[t] = 0.f;

    if (r < 30) {
        red[t] = dacc;
        __syncthreads();
        for (int s = 128; s > 0; s >>= 1) {
            if (t < s) red[t] += red[t + s];
            __syncthreads();
        }
        if (t == 0) Dvec[r] = red[0];
    }
}

// ---------------------------------------------------------------------------
// K1: MFMA row kernel — DOUBLE-BUFFERED LDS Ct staging, ONE barrier per K-tile.
// 64 rows/block, 4 waves; wave w owns rows w*16..w*16+15.
// Per iteration: issue next-tile CoefB loads into regs, compute pack+MFMA on
// Ct[cur], then ds_write the staged regs to Ct[cur^1] and barrier once —
// global-load latency hides under the compute phase.
// ---------------------------------------------------------------------------
__global__ __launch_bounds__(256, 4) void main_rows_kernel(
    const float* __restrict__ X, const float* __restrict__ W,
    const float* __restrict__ S, const float* __restrict__ bl,
    const float* __restrict__ br, const unsigned short* __restrict__ CoefB,
    const float* __restrict__ Dvec,
    float* __restrict__ out,          // [0]=ll, [1]=ce, [2..] = P row-major
    unsigned short* __restrict__ Pb, unsigned short* __restrict__ Lb,
    float* __restrict__ xl, float* __restrict__ xr)
{
    __shared__ __align__(16) unsigned short Ct[2][80 * 72];   // 22.5 KB

    const int t    = threadIdx.x;
    const int w    = t >> 6;
    const int l    = t & 63;
    const int l15  = l & 15;
    const int quad = l >> 4;
    const int k0q  = quad * 8;
    const int wavebase = blockIdx.x * 64 + w * 16;
    const bool valid = (wavebase < N_CELLS);     // uniform per wave (N%16==0)
    const float* __restrict__ xrow = X + (size_t)(wavebase + l15) * G_GENES;

    // staging assignment: thread t covers rows {t>>3, t>>3+32, (+64 if t<128)}
    const int srow = t >> 3;
    const int scol = (t & 7) << 3;
    const bool s3  = (t < 128);
    const unsigned short* __restrict__ cb0 = &CoefB[srow * KPAD + scol];

    f32x4 acc[5];
#pragma unroll
    for (int i = 0; i < 5; i++) acc[i] = (f32x4){0.f, 0.f, 0.f, 0.f};

    // stage K-tile 0 into Ct[0]
    {
        int4 p0 = *(const int4*)(cb0);
        int4 p1 = *(const int4*)(cb0 + 32 * KPAD);
        *(int4*)&Ct[0][srow * 72 + scol] = p0;
        *(int4*)&Ct[0][(srow + 32) * 72 + scol] = p1;
        if (s3) {
            int4 p2 = *(const int4*)(cb0 + 64 * KPAD);
            *(int4*)&Ct[0][(srow + 64) * 72 + scol] = p2;
        }
    }

    // prefetch X K-tile 0 (always in-bounds: k <= 63+7 < 1000)
    float4 c0a = make_float4(0.f, 0.f, 0.f, 0.f), c0b = c0a, c1a = c0a, c1b = c0a;
    if (valid) {
        c0a = *(const float4*)&xrow[k0q];
        c0b = *(const float4*)&xrow[k0q + 4];
        c1a = *(const float4*)&xrow[32 + k0q];
        c1b = *(const float4*)&xrow[32 + k0q + 4];
    }
    __syncthreads();                              // Ct[0] ready

#pragma unroll 2
    for (int kt = 0; kt < KPAD; kt += 64) {
        const int cur = (kt >> 6) & 1;
        const int ktn = kt + 64;

        // issue next Ct tile's global loads (consumed after compute)
        int4 q0, q1, q2;
        if (ktn < KPAD) {
            q0 = *(const int4*)(cb0 + ktn);
            q1 = *(const int4*)(cb0 + 32 * KPAD + ktn);
            if (s3) q2 = *(const int4*)(cb0 + 64 * KPAD + ktn);
        }

        // issue next tile's X loads (consumed next iteration)
        float4 n0a = make_float4(0.f, 0.f, 0.f, 0.f), n0b = n0a, n1a = n0a, n1b = n0a;
        if (valid && ktn < KPAD) {
            const int ka = ktn + k0q;          // ka+7 <= 991 always
            n0a = *(const float4*)&xrow[ka];
            n0b = *(const float4*)&xrow[ka + 4];
            const int kb = ktn + 32 + k0q;
            if (kb < G_GENES) {                // kb can reach 1016
                n1a = *(const float4*)&xrow[kb];
                n1b = *(const float4*)&xrow[kb + 4];
            }
        }

        // ---- pack + MFMA on current regs, B from Ct[cur] ----
        union { unsigned u[4]; bf16x8 v; } ua, u2;
        // ks = 0
        ua.u[0] = pack2(c0a.x, c0a.y); ua.u[1] = pack2(c0a.z, c0a.w);
        ua.u[2] = pack2(c0b.x, c0b.y); ua.u[3] = pack2(c0b.z, c0b.w);
        u2.u[0] = pack2(c0a.x * c0a.x, c0a.y * c0a.y);
        u2.u[1] = pack2(c0a.z * c0a.z, c0a.w * c0a.w);
        u2.u[2] = pack2(c0b.x * c0b.x, c0b.y * c0b.y);
        u2.u[3] = pack2(c0b.z * c0b.z, c0b.w * c0b.w);
#pragma unroll
        for (int nt = 0; nt < 5; nt++) {
            bf16x8 b = *(const bf16x8*)&Ct[cur][(nt * 16 + l15) * 72 + k0q];
            acc[nt] = __builtin_amdgcn_mfma_f32_16x16x32_bf16(
                nt < 2 ? u2.v : ua.v, b, acc[nt], 0, 0, 0);
        }
        // ks = 1
        ua.u[0] = pack2(c1a.x, c1a.y); ua.u[1] = pack2(c1a.z, c1a.w);
        ua.u[2] = pack2(c1b.x, c1b.y); ua.u[3] = pack2(c1b.z, c1b.w);
        u2.u[0] = pack2(c1a.x * c1a.x, c1a.y * c1a.y);
        u2.u[1] = pack2(c1a.z * c1a.z, c1a.w * c1a.w);
        u2.u[2] = pack2(c1b.x * c1b.x, c1b.y * c1b.y);
        u2.u[3] = pack2(c1b.z * c1b.z, c1b.w * c1b.w);
#pragma unroll
        for (int nt = 0; nt < 5; nt++) {
            bf16x8 b = *(const bf16x8*)&Ct[cur][(nt * 16 + l15) * 72 + 32 + k0q];
            acc[nt] = __builtin_amdgcn_mfma_f32_16x16x32_bf16(
                nt < 2 ? u2.v : ua.v, b, acc[nt], 0, 0, 0);
        }

        // write staged regs to the other buffer; one barrier per iteration
        if (ktn < KPAD) {
            *(int4*)&Ct[cur ^ 1][srow * 72 + scol] = q0;
            *(int4*)&Ct[cur ^ 1][(srow + 32) * 72 + scol] = q1;
            if (s3) *(int4*)&Ct[cur ^ 1][(srow + 64) * 72 + scol] = q2;
            __syncthreads();
        }

        c0a = n0a; c0b = n0b; c1a = n1a; c1b = n1b;
    }

    if (!valid) return;   // no barriers below

    // Epilogue (per wave). acc[nt][reg]: packed col = nt*16+l15, row = quad*4+reg.
    const int rbase = wavebase + quad * 4;
    const bool c2ok = (l15 < 14);
    const float d0 = Dvec[l15];
    const float d1 = c2ok ? Dvec[16 + l15] : 0.f;
    float llacc = 0.f;
#pragma unroll
    for (int r = 0; r < 4; r++) {
        const int row = rbase + r;
        float w0 = W[(size_t)row * 30 + l15];
        float w1 = c2ok ? W[(size_t)row * 30 + 16 + l15] : -1e30f;
        float m = fmaxf(w0, w1);
#pragma unroll
        for (int mm = 1; mm < 16; mm <<= 1) m = fmaxf(m, __shfl_xor(m, mm, 64));
        float e0 = __expf(w0 - m);
        float e1 = c2ok ? __expf(w1 - m) : 0.f;
        float s = e0 + e1;
#pragma unroll
        for (int mm = 1; mm < 16; mm <<= 1) s += __shfl_xor(s, mm, 64);
        float inv = 1.0f / s;
        float p0 = e0 * inv, p1 = e1 * inv;
        float Sn = S[row], Sn2 = Sn * Sn;
        float F0 = -0.5f * (acc[0][r] - 2.0f * Sn * acc[2][r] + Sn2 * d0);
        float F1 = -0.5f * (acc[1][r] - 2.0f * Sn * acc[3][r] + Sn2 * d1);
        float lp = p0 * F0 + (c2ok ? p1 * F1 : 0.f);
#pragma unroll
        for (int mm = 1; mm < 16; mm <<= 1) lp += __shfl_xor(lp, mm, 64);
        llacc += lp;

        out[2 + (size_t)row * 30 + l15] = p0;
        float lg0 = __logf(p0 + 1e-8f);
        Pb[(size_t)row * 32 + l15] = (unsigned short)f2bf_u(p0);
        Lb[(size_t)row * 32 + l15] = (unsigned short)f2bf_u(lg0);
        if (c2ok) {
            out[2 + (size_t)row * 30 + 16 + l15] = p1;
            float lg1 = __logf(p1 + 1e-8f);
            Pb[(size_t)row * 32 + 16 + l15] = (unsigned short)f2bf_u(p1);
            Lb[(size_t)row * 32 + 16 + l15] = (unsigned short)f2bf_u(lg1);
        } else {
            Pb[(size_t)row * 32 + 16 + l15] = 0;
            Lb[(size_t)row * 32 + 16 + l15] = 0;
        }
        if (l15 >= 14)                xl[(size_t)row * 8 + (l15 - 14)] = acc[3][r] + bl[l15 - 14];
        else if (l15 < 6)             xl[(size_t)row * 8 + (l15 + 2)]  = acc[4][r] + bl[l15 + 2];
        if (l15 >= 6 && l15 < 14)     xr[(size_t)row * 8 + (l15 - 6)]  = acc[4][r] + br[l15 - 6];
    }
    llacc += __shfl_xor(llacc, 16, 64);
    llacc += __shfl_xor(llacc, 32, 64);
    if (l == 0) atomicAdd(&out[0], llacc * (1.0f / N_CELLS));
}

// ---------------------------------------------------------------------------
// K2: SINGLE edge pass, 4 LANES PER EDGE (coalesced gathers).
// Lane j of each 4-lane group: classes 8j..8j+7 of Pb[src]/Lb[dst] (one int4;
// 4 lanes cover the full 64B row = one cache line), channels 2j..2j+1 of
// xl[src]/xr[dst] (float2). Two shfl_xor reduce dot and the attention logit.
// Accumulate (p, p*dot) into NREP replicated same-line slots by dst.
// ---------------------------------------------------------------------------
__global__ __launch_bounds__(256) void edge_pass(
    const int* __restrict__ ei, const float* __restrict__ xl,
    const float* __restrict__ xr, const float* __restrict__ att,
    const unsigned short* __restrict__ Pb, const unsigned short* __restrict__ Lb,
    float* __restrict__ dn4) {
    const int t = threadIdx.x;
    const int g = t >> 2;                     // group in block [0,64)
    const int j = t & 3;
    const int e = blockIdx.x * 64 + g;        // E = 12500*64 exactly
    const int src = ei[e];
    const int dst = ei[E_EDGES + e];

    // attention logit: lane j handles channels 2j, 2j+1
    float2 lv = *(const float2*)&xl[(size_t)src * 8 + j * 2];
    float2 rv = *(const float2*)&xr[(size_t)dst * 8 + j * 2];
    float2 av = *(const float2*)&att[j * 2];
    float ev = lrelu02(lv.x + rv.x) * av.x + lrelu02(lv.y + rv.y) * av.y;
    ev += __shfl_xor(ev, 1, 64);
    ev += __shfl_xor(ev, 2, 64);
    float p = __expf(ev);                     // |ev| ~ O(10): no max-subtraction

    // P[src]·logP[dst]: lane j handles classes 8j..8j+7
    int4 a = *(const int4*)&Pb[(size_t)src * 32 + j * 8];
    int4 b = *(const int4*)&Lb[(size_t)dst * 32 + j * 8];
    float dot = dp4(a, b);
    dot += __shfl_xor(dot, 1, 64);
    dot += __shfl_xor(dot, 2, 64);

    float* base = &dn4[((size_t)(blockIdx.x & (NREP - 1)) * N_CELLS + dst) * 2];
    if (j == 0)      atomicAdd(base, p);
    else if (j == 1) atomicAdd(base + 1, p * dot);
}

// ---------------------------------------------------------------------------
// K3: finalize — fold replicas, ce = -sum numer/denom / N
// ---------------------------------------------------------------------------
__global__ __launch_bounds__(256) void finalize_kernel(const float* __restrict__ dn4,
                                                       float* __restrict__ out) {
    const int t = threadIdx.x;
    const int i = blockIdx.x * 256 + t;
    float c = 0.f;
    if (i < N_CELLS) {
        float d  = (dn4[(size_t)i * 2]     + dn4[((size_t)N_CELLS + i) * 2]) +
                   (dn4[((size_t)2 * N_CELLS + i) * 2] + dn4[((size_t)3 * N_CELLS + i) * 2]);
        float nm = (dn4[(size_t)i * 2 + 1] + dn4[((size_t)N_CELLS + i) * 2 + 1]) +
                   (dn4[((size_t)2 * N_CELLS + i) * 2 + 1] + dn4[((size_t)3 * N_CELLS + i) * 2 + 1]);
        c = nm / (d + 1e-16f);
    }
#pragma unroll
    for (int m = 1; m < 64; m <<= 1) c += __shfl_xor(c, m, 64);
    __shared__ float wsum[4];
    if ((t & 63) == 0) wsum[t >> 6] = c;
    __syncthreads();
    if (t == 0)
        atomicAdd(&out[1], -(wsum[0] + wsum[1] + wsum[2] + wsum[3]) * (1.0f / N_CELLS));
}

// ---------------------------------------------------------------------------
// launch
// ---------------------------------------------------------------------------
extern "C" void kernel_launch(void* const* d_in, const int* in_sizes, int n_in,
                              void* d_out, int out_size, void* d_ws, size_t ws_size,
                              hipStream_t stream) {
    const float* X   = (const float*)d_in[0];
    const float* Mu  = (const float*)d_in[1];
    const float* Var = (const float*)d_in[2];
    const int*   ei  = (const int*)d_in[3];
    const float* W   = (const float*)d_in[4];
    const float* S   = (const float*)d_in[5];
    const float* Wl  = (const float*)d_in[6];
    const float* bl  = (const float*)d_in[7];
    const float* Wr  = (const float*)d_in[8];
    const float* br  = (const float*)d_in[9];
    const float* att = (const float*)d_in[10];

    float* out = (float*)d_out;

    // ws layout (float offsets), total 2,840,992 fl = 11.36 MB
    float* wsf = (float*)d_ws;
    unsigned short* CoefB  = (unsigned short*)wsf;             // 80*1024 us = 40960 fl
    float* Dvec            = wsf + 40960;                      // 32
    unsigned short* Pb     = (unsigned short*)(wsf + 40992);   // N*32 us = 800000 fl
    unsigned short* Lb     = (unsigned short*)(wsf + 840992);  // N*32 us
    float* xl              = wsf + 1640992;                    // N*8
    float* xr              = wsf + 2040992;                    // N*8
    float* dn4             = wsf + 2440992;                    // NREP*N*2 = 400000

    prep_kernel<<<80, 256, 0, stream>>>(Mu, Var, Wl, Wr, CoefB, Dvec, dn4, out);
    main_rows_kernel<<<(N_CELLS + 63) / 64, 256, 0, stream>>>(
        X, W, S, bl, br, CoefB, Dvec, out, Pb, Lb, xl, xr);
    edge_pass<<<E_EDGES / 64, 256, 0, stream>>>(ei, xl, xr, att, Pb, Lb, dn4);
    finalize_kernel<<<(N_CELLS + 255) / 256, 256, 0, stream>>>(dn4, out);
}

// Round 4
// 442.813 us; speedup vs baseline: 1.0676x; 1.0018x over previous
//
#include <hip/hip_runtime.h>
#include <hip/hip_bf16.h>
#include <math.h>

// Problem constants
#define N_CELLS 50000
#define C_CLS   30
#define G_GENES 1000
#define E_EDGES 800000
#define KPAD    1024
#define NREP    4

typedef __attribute__((ext_vector_type(8))) short bf16x8;
typedef __attribute__((ext_vector_type(4))) float f32x4;

// fp32 -> bf16 (RNE), raw ushort payload
__device__ __forceinline__ unsigned f2bf_u(float f) {
    unsigned u = __float_as_uint(f);
    return (u + 0x7fffu + ((u >> 16) & 1u)) >> 16;
}
// packed 2x f32->bf16 via v_cvt_pk_bf16_f32
__device__ __forceinline__ unsigned pack2(float lo, float hi) {
    union { __hip_bfloat162 h; unsigned u; } cv;
    cv.h = __float22bfloat162_rn(make_float2(lo, hi));
    return cv.u;
}
__device__ __forceinline__ float bf2f(unsigned short u) {
    return __uint_as_float(((unsigned)u) << 16);
}

__device__ __forceinline__ float lrelu02(float v) { return v > 0.f ? v : 0.2f * v; }

// LDS-only barrier: lgkmcnt(0) drain + raw s_barrier. Unlike __syncthreads()
// this does NOT drain vmcnt, so global prefetch loads stay in flight across
// the barrier (the whole point of the register pipeline below).
__device__ __forceinline__ void lds_barrier() {
    asm volatile("s_waitcnt lgkmcnt(0)" ::: "memory");
    __builtin_amdgcn_s_barrier();
}

// dot of 8 bf16 pairs packed in one int4
__device__ __forceinline__ float dp4(int4 a, int4 b) {
    const unsigned* ua = (const unsigned*)&a;
    const unsigned* ub = (const unsigned*)&b;
    float s = 0.f;
#pragma unroll
    for (int i = 0; i < 4; i++) {
        float al = __uint_as_float(ua[i] << 16);
        float ah = __uint_as_float(ua[i] & 0xffff0000u);
        float bl = __uint_as_float(ub[i] << 16);
        float bh = __uint_as_float(ub[i] & 0xffff0000u);
        s += al * bl + ah * bh;
    }
    return s;
}

// ---------------------------------------------------------------------------
// K0: pack CoefB bf16 [80][1024] + Dvec[30]; zero dn4 accumulators + out[0..1].
// ---------------------------------------------------------------------------
__global__ void prep_kernel(const float* __restrict__ Mu, const float* __restrict__ Var,
                            const float* __restrict__ Wl, const float* __restrict__ Wr,
                            unsigned short* __restrict__ CoefB, float* __restrict__ Dvec,
                            float* __restrict__ dn4, float* __restrict__ out) {
    const int r = blockIdx.x;
    const int t = threadIdx.x;
    __shared__ float red[256];
    float dacc = 0.f;
    for (int g = t; g < KPAD; g += 256) {
        float v = 0.f;
        if (g < G_GENES) {
            if (r < 30) {
                float iv = 1.0f / Var[r * G_GENES + g];
                float mu = Mu[r * G_GENES + g];
                v = iv;
                dacc += mu * mu * iv;
            } else if (r >= 32) {
                int i = r - 32;
                if (i < 30)      v = Mu[i * G_GENES + g] / Var[i * G_GENES + g];
                else if (i < 38) v = Wl[(i - 30) * G_GENES + g];
                else if (i < 46) v = Wr[(i - 38) * G_GENES + g];
            }
        }
        CoefB[r * KPAD + g] = (unsigned short)f2bf_u(v);
    }
    // zero the interleaved (denom,numer) replicated accumulators
    for (int i = blockIdx.x * 256 + t; i < N_CELLS * NREP * 2; i += 80 * 256) dn4[i] = 0.f;
    if (r == 31 && t < 2) out[t] = 0.f;

    if (r < 30) {
        red[t] = dacc;
        __syncthreads();
        for (int s = 128; s > 0; s >>= 1) {
            if (t < s) red[t] += red[t + s];
            __syncthreads();
        }
        if (t == 0) Dvec[r] = red[0];
    }
}

// ---------------------------------------------------------------------------
// K1: MFMA row kernel — double-buffered LDS, depth-2 register pipeline,
// LDS-only barriers (vmcnt survives the barrier).
//   X loads:     issued 2 tiles ahead (regs xc=tile i, xn=tile i+1, xm=i+2)
//   CoefB loads: issued 1 tile ahead  (regs qc=tile i+1, ds_written at iter i)
// One lds_barrier per iteration.
// ---------------------------------------------------------------------------
__global__ __launch_bounds__(256, 3) void main_rows_kernel(
    const float* __restrict__ X, const float* __restrict__ W,
    const float* __restrict__ S, const float* __restrict__ bl,
    const float* __restrict__ br, const unsigned short* __restrict__ CoefB,
    const float* __restrict__ Dvec,
    float* __restrict__ out,          // [0]=ll, [1]=ce, [2..] = P row-major
    unsigned short* __restrict__ Pb, unsigned short* __restrict__ Lb,
    float* __restrict__ xl, float* __restrict__ xr)
{
    __shared__ __align__(16) unsigned short Ct[2][80 * 72];   // 22.5 KB

    const int t    = threadIdx.x;
    const int w    = t >> 6;
    const int l    = t & 63;
    const int l15  = l & 15;
    const int quad = l >> 4;
    const int k0q  = quad * 8;
    const int wavebase = blockIdx.x * 64 + w * 16;
    const bool valid = (wavebase < N_CELLS);     // uniform per wave (N%16==0)
    const float* __restrict__ xrow = X + (size_t)(wavebase + l15) * G_GENES;

    // staging assignment: thread t covers rows {t>>3, t>>3+32, (+64 if t<128)}
    const int srow = t >> 3;
    const int scol = (t & 7) << 3;
    const bool s3  = (t < 128);                  // wave-uniform (waves 0,1)
    const unsigned short* __restrict__ cb0 = &CoefB[srow * KPAD + scol];

    f32x4 acc[5];
#pragma unroll
    for (int i = 0; i < 5; i++) acc[i] = (f32x4){0.f, 0.f, 0.f, 0.f};

    // --- prologue ---
    // stage K-tile 0 directly into Ct[0]
    {
        int4 p0 = *(const int4*)(cb0);
        int4 p1 = *(const int4*)(cb0 + 32 * KPAD);
        *(int4*)&Ct[0][srow * 72 + scol] = p0;
        *(int4*)&Ct[0][(srow + 32) * 72 + scol] = p1;
        if (s3) {
            int4 p2 = *(const int4*)(cb0 + 64 * KPAD);
            *(int4*)&Ct[0][(srow + 64) * 72 + scol] = p2;
        }
    }
    // CoefB tile 1 -> regs (ds_written at iter 0)
    int4 qc0 = *(const int4*)(cb0 + 64);
    int4 qc1 = *(const int4*)(cb0 + 32 * KPAD + 64);
    int4 qc2 = make_int4(0, 0, 0, 0);
    if (s3) qc2 = *(const int4*)(cb0 + 64 * KPAD + 64);

    // X tiles 0 and 1 -> regs (all in-bounds: k <= 127+... < 1000)
    float4 z4 = make_float4(0.f, 0.f, 0.f, 0.f);
    float4 c0a = z4, c0b = z4, c1a = z4, c1b = z4;   // tile 0
    float4 n0a = z4, n0b = z4, n1a = z4, n1b = z4;   // tile 1
    if (valid) {
        c0a = *(const float4*)&xrow[k0q];
        c0b = *(const float4*)&xrow[k0q + 4];
        c1a = *(const float4*)&xrow[32 + k0q];
        c1b = *(const float4*)&xrow[32 + k0q + 4];
        n0a = *(const float4*)&xrow[64 + k0q];
        n0b = *(const float4*)&xrow[64 + k0q + 4];
        n1a = *(const float4*)&xrow[96 + k0q];
        n1b = *(const float4*)&xrow[96 + k0q + 4];
    }
    lds_barrier();                                // Ct[0] ready

#pragma unroll 2
    for (int kt = 0; kt < KPAD; kt += 64) {
        const int cur = (kt >> 6) & 1;
        const int kt2 = kt + 128;

        // depth-2 prefetches (tile i+2): CoefB -> qn regs, X -> m regs
        int4 qn0 = make_int4(0, 0, 0, 0), qn1 = qn0, qn2 = qn0;
        float4 m0a = z4, m0b = z4, m1a = z4, m1b = z4;
        if (kt2 < KPAD) {
            qn0 = *(const int4*)(cb0 + kt2);
            qn1 = *(const int4*)(cb0 + 32 * KPAD + kt2);
            if (s3) qn2 = *(const int4*)(cb0 + 64 * KPAD + kt2);
            if (valid) {
                const int ka = kt2 + k0q;          // ka+7 <= 991 always
                m0a = *(const float4*)&xrow[ka];
                m0b = *(const float4*)&xrow[ka + 4];
                const int kb = kt2 + 32 + k0q;
                if (kb < G_GENES) {                // kb can reach 1016
                    m1a = *(const float4*)&xrow[kb];
                    m1b = *(const float4*)&xrow[kb + 4];
                }
            }
        }

        // ---- pack + MFMA on current X regs, B from Ct[cur] ----
        union { unsigned u[4]; bf16x8 v; } ua, u2;
        // ks = 0
        ua.u[0] = pack2(c0a.x, c0a.y); ua.u[1] = pack2(c0a.z, c0a.w);
        ua.u[2] = pack2(c0b.x, c0b.y); ua.u[3] = pack2(c0b.z, c0b.w);
        u2.u[0] = pack2(c0a.x * c0a.x, c0a.y * c0a.y);
        u2.u[1] = pack2(c0a.z * c0a.z, c0a.w * c0a.w);
        u2.u[2] = pack2(c0b.x * c0b.x, c0b.y * c0b.y);
        u2.u[3] = pack2(c0b.z * c0b.z, c0b.w * c0b.w);
#pragma unroll
        for (int nt = 0; nt < 5; nt++) {
            bf16x8 b = *(const bf16x8*)&Ct[cur][(nt * 16 + l15) * 72 + k0q];
            acc[nt] = __builtin_amdgcn_mfma_f32_16x16x32_bf16(
                nt < 2 ? u2.v : ua.v, b, acc[nt], 0, 0, 0);
        }
        // ks = 1
        ua.u[0] = pack2(c1a.x, c1a.y); ua.u[1] = pack2(c1a.z, c1a.w);
        ua.u[2] = pack2(c1b.x, c1b.y); ua.u[3] = pack2(c1b.z, c1b.w);
        u2.u[0] = pack2(c1a.x * c1a.x, c1a.y * c1a.y);
        u2.u[1] = pack2(c1a.z * c1a.z, c1a.w * c1a.w);
        u2.u[2] = pack2(c1b.x * c1b.x, c1b.y * c1b.y);
        u2.u[3] = pack2(c1b.z * c1b.z, c1b.w * c1b.w);
#pragma unroll
        for (int nt = 0; nt < 5; nt++) {
            bf16x8 b = *(const bf16x8*)&Ct[cur][(nt * 16 + l15) * 72 + 32 + k0q];
            acc[nt] = __builtin_amdgcn_mfma_f32_16x16x32_bf16(
                nt < 2 ? u2.v : ua.v, b, acc[nt], 0, 0, 0);
        }

        // ds_write tile i+1 (regs loaded last iter) into the other buffer.
        // Safe even if scheduled early: Ct[cur^1] holds tile i-1 data, fully
        // consumed before the previous barrier.
        if (kt + 64 < KPAD) {
            *(int4*)&Ct[cur ^ 1][srow * 72 + scol] = qc0;
            *(int4*)&Ct[cur ^ 1][(srow + 32) * 72 + scol] = qc1;
            if (s3) *(int4*)&Ct[cur ^ 1][(srow + 64) * 72 + scol] = qc2;
            lds_barrier();                        // LDS-only drain; vmcnt rides
        }

        // rotate register pipeline
        c0a = n0a; c0b = n0b; c1a = n1a; c1b = n1b;
        n0a = m0a; n0b = m0b; n1a = m1a; n1b = m1b;
        qc0 = qn0; qc1 = qn1; qc2 = qn2;
    }

    if (!valid) return;   // no barriers below

    // Epilogue (per wave). acc[nt][reg]: packed col = nt*16+l15, row = quad*4+reg.
    const int rbase = wavebase + quad * 4;
    const bool c2ok = (l15 < 14);
    const float d0 = Dvec[l15];
    const float d1 = c2ok ? Dvec[16 + l15] : 0.f;
    float llacc = 0.f;
#pragma unroll
    for (int r = 0; r < 4; r++) {
        const int row = rbase + r;
        float w0 = W[(size_t)row * 30 + l15];
        float w1 = c2ok ? W[(size_t)row * 30 + 16 + l15] : -1e30f;
        float m = fmaxf(w0, w1);
#pragma unroll
        for (int mm = 1; mm < 16; mm <<= 1) m = fmaxf(m, __shfl_xor(m, mm, 64));
        float e0 = __expf(w0 - m);
        float e1 = c2ok ? __expf(w1 - m) : 0.f;
        float s = e0 + e1;
#pragma unroll
        for (int mm = 1; mm < 16; mm <<= 1) s += __shfl_xor(s, mm, 64);
        float inv = 1.0f / s;
        float p0 = e0 * inv, p1 = e1 * inv;
        float Sn = S[row], Sn2 = Sn * Sn;
        float F0 = -0.5f * (acc[0][r] - 2.0f * Sn * acc[2][r] + Sn2 * d0);
        float F1 = -0.5f * (acc[1][r] - 2.0f * Sn * acc[3][r] + Sn2 * d1);
        float lp = p0 * F0 + (c2ok ? p1 * F1 : 0.f);
#pragma unroll
        for (int mm = 1; mm < 16; mm <<= 1) lp += __shfl_xor(lp, mm, 64);
        llacc += lp;

        out[2 + (size_t)row * 30 + l15] = p0;
        float lg0 = __logf(p0 + 1e-8f);
        Pb[(size_t)row * 32 + l15] = (unsigned short)f2bf_u(p0);
        Lb[(size_t)row * 32 + l15] = (unsigned short)f2bf_u(lg0);
        if (c2ok) {
            out[2 + (size_t)row * 30 + 16 + l15] = p1;
            float lg1 = __logf(p1 + 1e-8f);
            Pb[(size_t)row * 32 + 16 + l15] = (unsigned short)f2bf_u(p1);
            Lb[(size_t)row * 32 + 16 + l15] = (unsigned short)f2bf_u(lg1);
        } else {
            Pb[(size_t)row * 32 + 16 + l15] = 0;
            Lb[(size_t)row * 32 + 16 + l15] = 0;
        }
        if (l15 >= 14)                xl[(size_t)row * 8 + (l15 - 14)] = acc[3][r] + bl[l15 - 14];
        else if (l15 < 6)             xl[(size_t)row * 8 + (l15 + 2)]  = acc[4][r] + bl[l15 + 2];
        if (l15 >= 6 && l15 < 14)     xr[(size_t)row * 8 + (l15 - 6)]  = acc[4][r] + br[l15 - 6];
    }
    llacc += __shfl_xor(llacc, 16, 64);
    llacc += __shfl_xor(llacc, 32, 64);
    if (l == 0) atomicAdd(&out[0], llacc * (1.0f / N_CELLS));
}

// ---------------------------------------------------------------------------
// K2: SINGLE edge pass, 4 lanes/edge (coalesced gathers), (p, p*dot) pair
// atomics into NREP replicated same-line slots by dst.
// ---------------------------------------------------------------------------
__global__ __launch_bounds__(256) void edge_pass(
    const int* __restrict__ ei, const float* __restrict__ xl,
    const float* __restrict__ xr, const float* __restrict__ att,
    const unsigned short* __restrict__ Pb, const unsigned short* __restrict__ Lb,
    float* __restrict__ dn4) {
    const int t = threadIdx.x;
    const int g = t >> 2;                     // group in block [0,64)
    const int j = t & 3;
    const int e = blockIdx.x * 64 + g;        // E = 12500*64 exactly
    const int src = ei[e];
    const int dst = ei[E_EDGES + e];

    float2 lv = *(const float2*)&xl[(size_t)src * 8 + j * 2];
    float2 rv = *(const float2*)&xr[(size_t)dst * 8 + j * 2];
    float2 av = *(const float2*)&att[j * 2];
    float ev = lrelu02(lv.x + rv.x) * av.x + lrelu02(lv.y + rv.y) * av.y;
    ev += __shfl_xor(ev, 1, 64);
    ev += __shfl_xor(ev, 2, 64);
    float p = __expf(ev);                     // |ev| ~ O(10): no max-subtraction

    int4 a = *(const int4*)&Pb[(size_t)src * 32 + j * 8];
    int4 b = *(const int4*)&Lb[(size_t)dst * 32 + j * 8];
    float dot = dp4(a, b);
    dot += __shfl_xor(dot, 1, 64);
    dot += __shfl_xor(dot, 2, 64);

    float* base = &dn4[((size_t)(blockIdx.x & (NREP - 1)) * N_CELLS + dst) * 2];
    if (j == 0)      atomicAdd(base, p);
    else if (j == 1) atomicAdd(base + 1, p * dot);
}

// ---------------------------------------------------------------------------
// K3: finalize — fold replicas, ce = -sum numer/denom / N
// ---------------------------------------------------------------------------
__global__ __launch_bounds__(256) void finalize_kernel(const float* __restrict__ dn4,
                                                       float* __restrict__ out) {
    const int t = threadIdx.x;
    const int i = blockIdx.x * 256 + t;
    float c = 0.f;
    if (i < N_CELLS) {
        float d  = (dn4[(size_t)i * 2]     + dn4[((size_t)N_CELLS + i) * 2]) +
                   (dn4[((size_t)2 * N_CELLS + i) * 2] + dn4[((size_t)3 * N_CELLS + i) * 2]);
        float nm = (dn4[(size_t)i * 2 + 1] + dn4[((size_t)N_CELLS + i) * 2 + 1]) +
                   (dn4[((size_t)2 * N_CELLS + i) * 2 + 1] + dn4[((size_t)3 * N_CELLS + i) * 2 + 1]);
        c = nm / (d + 1e-16f);
    }
#pragma unroll
    for (int m = 1; m < 64; m <<= 1) c += __shfl_xor(c, m, 64);
    __shared__ float wsum[4];
    if ((t & 63) == 0) wsum[t >> 6] = c;
    __syncthreads();
    if (t == 0)
        atomicAdd(&out[1], -(wsum[0] + wsum[1] + wsum[2] + wsum[3]) * (1.0f / N_CELLS));
}

// ---------------------------------------------------------------------------
// launch
// ---------------------------------------------------------------------------
extern "C" void kernel_launch(void* const* d_in, const int* in_sizes, int n_in,
                              void* d_out, int out_size, void* d_ws, size_t ws_size,
                              hipStream_t stream) {
    const float* X   = (const float*)d_in[0];
    const float* Mu  = (const float*)d_in[1];
    const float* Var = (const float*)d_in[2];
    const int*   ei  = (const int*)d_in[3];
    const float* W   = (const float*)d_in[4];
    const float* S   = (const float*)d_in[5];
    const float* Wl  = (const float*)d_in[6];
    const float* bl  = (const float*)d_in[7];
    const float* Wr  = (const float*)d_in[8];
    const float* br  = (const float*)d_in[9];
    const float* att = (const float*)d_in[10];

    float* out = (float*)d_out;

    // ws layout (float offsets)
    float* wsf = (float*)d_ws;
    unsigned short* CoefB  = (unsigned short*)wsf;             // 80*1024 us = 40960 fl
    float* Dvec            = wsf + 40960;                      // 32
    unsigned short* Pb     = (unsigned short*)(wsf + 40992);   // N*32 us = 800000 fl
    unsigned short* Lb     = (unsigned short*)(wsf + 840992);  // N*32 us
    float* xl              = wsf + 1640992;                    // N*8
    float* xr              = wsf + 2040992;                    // N*8
    float* dn4             = wsf + 2440992;                    // NREP*N*2 = 400000

    prep_kernel<<<80, 256, 0, stream>>>(Mu, Var, Wl, Wr, CoefB, Dvec, dn4, out);
    main_rows_kernel<<<(N_CELLS + 63) / 64, 256, 0, stream>>>(
        X, W, S, bl, br, CoefB, Dvec, out, Pb, Lb, xl, xr);
    edge_pass<<<E_EDGES / 64, 256, 0, stream>>>(ei, xl, xr, att, Pb, Lb, dn4);
    finalize_kernel<<<(N_CELLS + 255) / 256, 256, 0, stream>>>(dn4, out);
}

// Round 5
// 437.164 us; speedup vs baseline: 1.0814x; 1.0129x over previous
//
#include <hip/hip_runtime.h>
#include <hip/hip_bf16.h>
#include <math.h>

// Problem constants
#define N_CELLS 50000
#define C_CLS   30
#define G_GENES 1000
#define E_EDGES 800000
#define KPAD    1024
#define NREP    4

typedef __attribute__((ext_vector_type(8))) short bf16x8;
typedef __attribute__((ext_vector_type(4))) float f32x4;

// fp32 -> bf16 (RNE), raw ushort payload
__device__ __forceinline__ unsigned f2bf_u(float f) {
    unsigned u = __float_as_uint(f);
    return (u + 0x7fffu + ((u >> 16) & 1u)) >> 16;
}
// packed 2x f32->bf16 via v_cvt_pk_bf16_f32
__device__ __forceinline__ unsigned pack2(float lo, float hi) {
    union { __hip_bfloat162 h; unsigned u; } cv;
    cv.h = __float22bfloat162_rn(make_float2(lo, hi));
    return cv.u;
}
__device__ __forceinline__ float bf2f(unsigned short u) {
    return __uint_as_float(((unsigned)u) << 16);
}

__device__ __forceinline__ float lrelu02(float v) { return v > 0.f ? v : 0.2f * v; }

// LDS-only barrier: lgkmcnt(0) drain + raw s_barrier (vmcnt rides across).
__device__ __forceinline__ void lds_barrier() {
    asm volatile("s_waitcnt lgkmcnt(0)" ::: "memory");
    __builtin_amdgcn_s_barrier();
}

// pack a pair of float4 (8 consecutive k) into linear and squared bf16x8
__device__ __forceinline__ void pack_pair(const float4& A, const float4& B,
                                          bf16x8* lin, bf16x8* sq) {
    union { unsigned u[4]; bf16x8 v; } ua, u2;
    ua.u[0] = pack2(A.x, A.y); ua.u[1] = pack2(A.z, A.w);
    ua.u[2] = pack2(B.x, B.y); ua.u[3] = pack2(B.z, B.w);
    u2.u[0] = pack2(A.x * A.x, A.y * A.y); u2.u[1] = pack2(A.z * A.z, A.w * A.w);
    u2.u[2] = pack2(B.x * B.x, B.y * B.y); u2.u[3] = pack2(B.z * B.z, B.w * B.w);
    *lin = ua.v; *sq = u2.v;
}

// dot of 8 bf16 pairs packed in one int4
__device__ __forceinline__ float dp4(int4 a, int4 b) {
    const unsigned* ua = (const unsigned*)&a;
    const unsigned* ub = (const unsigned*)&b;
    float s = 0.f;
#pragma unroll
    for (int i = 0; i < 4; i++) {
        float al = __uint_as_float(ua[i] << 16);
        float ah = __uint_as_float(ua[i] & 0xffff0000u);
        float bl = __uint_as_float(ub[i] << 16);
        float bh = __uint_as_float(ub[i] & 0xffff0000u);
        s += al * bl + ah * bh;
    }
    return s;
}

// ---------------------------------------------------------------------------
// K0: pack CoefB bf16 [80][1024] + Dvec[30]; zero dn4 accumulators + out[0..1].
// ---------------------------------------------------------------------------
__global__ void prep_kernel(const float* __restrict__ Mu, const float* __restrict__ Var,
                            const float* __restrict__ Wl, const float* __restrict__ Wr,
                            unsigned short* __restrict__ CoefB, float* __restrict__ Dvec,
                            float* __restrict__ dn4, float* __restrict__ out) {
    const int r = blockIdx.x;
    const int t = threadIdx.x;
    __shared__ float red[256];
    float dacc = 0.f;
    for (int g = t; g < KPAD; g += 256) {
        float v = 0.f;
        if (g < G_GENES) {
            if (r < 30) {
                float iv = 1.0f / Var[r * G_GENES + g];
                float mu = Mu[r * G_GENES + g];
                v = iv;
                dacc += mu * mu * iv;
            } else if (r >= 32) {
                int i = r - 32;
                if (i < 30)      v = Mu[i * G_GENES + g] / Var[i * G_GENES + g];
                else if (i < 38) v = Wl[(i - 30) * G_GENES + g];
                else if (i < 46) v = Wr[(i - 38) * G_GENES + g];
            }
        }
        CoefB[r * KPAD + g] = (unsigned short)f2bf_u(v);
    }
    for (int i = blockIdx.x * 256 + t; i < N_CELLS * NREP * 2; i += 80 * 256) dn4[i] = 0.f;
    if (r == 31 && t < 2) out[t] = 0.f;

    if (r < 30) {
        red[t] = dacc;
        __syncthreads();
        for (int s = 128; s > 0; s >>= 1) {
            if (t < s) red[t] += red[t + s];
            __syncthreads();
        }
        if (t == 0) Dvec[r] = red[0];
    }
}

// ---------------------------------------------------------------------------
// K1: MFMA row kernel — 32 rows/block (2 waves), grid 1563 (6 blocks/CU,
// LDS-capped), fully-unrolled 16-step K loop with SSA ping-pong prefetch:
//   X: depth-2 (loaded at it, consumed at it+2); B: depth-1 via regs->LDS.
// Branchless clamped addresses (CoefB zero-padding for g>=1000 annihilates
// any clamped garbage). One LDS-only barrier per iteration.
// ---------------------------------------------------------------------------
__global__ __launch_bounds__(128, 3) void main_rows_kernel(
    const float* __restrict__ X, const float* __restrict__ W,
    const float* __restrict__ S, const float* __restrict__ bl,
    const float* __restrict__ br, const unsigned short* __restrict__ CoefB,
    const float* __restrict__ Dvec,
    float* __restrict__ out,          // [0]=ll, [1]=ce, [2..] = P row-major
    unsigned short* __restrict__ Pb, unsigned short* __restrict__ Lb,
    float* __restrict__ xl, float* __restrict__ xr)
{
    __shared__ __align__(16) unsigned short Ct[2][80 * 72];   // 22.5 KB

    const int t    = threadIdx.x;
    const int w    = t >> 6;
    const int l    = t & 63;
    const int l15  = l & 15;
    const int quad = l >> 4;
    const int k0q  = quad * 8;
    const int wavebase = blockIdx.x * 32 + w * 16;
    const bool valid = (wavebase < N_CELLS);     // uniform per wave
    const float* __restrict__ xrow = X + (size_t)(wavebase + l15) * G_GENES;

    // staging: thread t covers rows {srow + 16j, j=0..4}, cols scol..scol+7
    const int srow = t >> 3;                     // 0..15
    const int scol = (t & 7) << 3;               // 0,8,..,56
    const unsigned short* __restrict__ cb0 = &CoefB[srow * KPAD + scol];

    f32x4 acc[5];
#pragma unroll
    for (int i = 0; i < 5; i++) acc[i] = (f32x4){0.f, 0.f, 0.f, 0.f};

    // --- prologue: B tile 0 -> Ct[0]; B tile 1 -> qb; X tiles 0,1 -> xs ---
    {
#pragma unroll
        for (int j = 0; j < 5; j++) {
            int4 p = *(const int4*)(cb0 + 16 * j * KPAD);
            *(int4*)&Ct[0][(srow + 16 * j) * 72 + scol] = p;
        }
    }
    int4 qb[5];
#pragma unroll
    for (int j = 0; j < 5; j++) qb[j] = *(const int4*)(cb0 + 16 * j * KPAD + 64);

    const float4 z4 = make_float4(0.f, 0.f, 0.f, 0.f);
    float4 xs[2][4];
#pragma unroll
    for (int sl = 0; sl < 2; sl++)
#pragma unroll
        for (int i = 0; i < 4; i++) xs[sl][i] = z4;
    if (valid) {
        xs[0][0] = *(const float4*)&xrow[k0q];
        xs[0][1] = *(const float4*)&xrow[k0q + 4];
        xs[0][2] = *(const float4*)&xrow[32 + k0q];
        xs[0][3] = *(const float4*)&xrow[32 + k0q + 4];
        xs[1][0] = *(const float4*)&xrow[64 + k0q];
        xs[1][1] = *(const float4*)&xrow[64 + k0q + 4];
        xs[1][2] = *(const float4*)&xrow[96 + k0q];
        xs[1][3] = *(const float4*)&xrow[96 + k0q + 4];
    }
    lds_barrier();                                // Ct[0] ready

#pragma unroll
    for (int it = 0; it < 16; ++it) {
        const int sl = it & 1;

        // depth-2 X prefetch: tile it+2 (issued first, consumed 2 iters later)
        float4 t0 = z4, t1 = z4, t2 = z4, t3 = z4;
        if (it < 14) {
            const int kt2 = (it + 2) * 64;
            if (valid) {
                const int ka = kt2 + k0q;          // ka+7 <= 991 always
                t0 = *(const float4*)&xrow[ka];
                t1 = *(const float4*)&xrow[ka + 4];
                int kb = kt2 + 32 + k0q;           // tile 15: 992+k0q
                if (kb > 992) kb = 0;              // clamp; coef==0 kills garbage
                t2 = *(const float4*)&xrow[kb];
                t3 = *(const float4*)&xrow[kb + 4];
            }
        }
        // depth-1 B prefetch: tile it+2 -> regs (ds_written next iter)
        int4 n0, n1, n2, n3, n4;
        if (it < 14) {
            const int kt2 = (it + 2) * 64;
            n0 = *(const int4*)(cb0 + kt2);
            n1 = *(const int4*)(cb0 + 16 * KPAD + kt2);
            n2 = *(const int4*)(cb0 + 32 * KPAD + kt2);
            n3 = *(const int4*)(cb0 + 48 * KPAD + kt2);
            n4 = *(const int4*)(cb0 + 64 * KPAD + kt2);
        }

        // ---- pack + MFMA on xs[sl], B from Ct[sl] ----
        bf16x8 va, v2;
        pack_pair(xs[sl][0], xs[sl][1], &va, &v2);
#pragma unroll
        for (int nt = 0; nt < 5; nt++) {
            bf16x8 b = *(const bf16x8*)&Ct[sl][(nt * 16 + l15) * 72 + k0q];
            acc[nt] = __builtin_amdgcn_mfma_f32_16x16x32_bf16(
                nt < 2 ? v2 : va, b, acc[nt], 0, 0, 0);
        }
        pack_pair(xs[sl][2], xs[sl][3], &va, &v2);
#pragma unroll
        for (int nt = 0; nt < 5; nt++) {
            bf16x8 b = *(const bf16x8*)&Ct[sl][(nt * 16 + l15) * 72 + 32 + k0q];
            acc[nt] = __builtin_amdgcn_mfma_f32_16x16x32_bf16(
                nt < 2 ? v2 : va, b, acc[nt], 0, 0, 0);
        }

        // stage B tile it+1 (qb) into the other buffer; one barrier/iter
        if (it < 15) {
            *(int4*)&Ct[sl ^ 1][ srow       * 72 + scol] = qb[0];
            *(int4*)&Ct[sl ^ 1][(srow + 16) * 72 + scol] = qb[1];
            *(int4*)&Ct[sl ^ 1][(srow + 32) * 72 + scol] = qb[2];
            *(int4*)&Ct[sl ^ 1][(srow + 48) * 72 + scol] = qb[3];
            *(int4*)&Ct[sl ^ 1][(srow + 64) * 72 + scol] = qb[4];
            lds_barrier();
        }
        // SSA rotation (renamed by full unroll)
        if (it < 14) {
            xs[sl][0] = t0; xs[sl][1] = t1; xs[sl][2] = t2; xs[sl][3] = t3;
            qb[0] = n0; qb[1] = n1; qb[2] = n2; qb[3] = n3; qb[4] = n4;
        }
    }

    if (!valid) return;   // no barriers below

    // Epilogue (per wave). acc[nt][reg]: packed col = nt*16+l15, row = quad*4+reg.
    const int rbase = wavebase + quad * 4;
    const bool c2ok = (l15 < 14);
    const float d0 = Dvec[l15];
    const float d1 = c2ok ? Dvec[16 + l15] : 0.f;
    float llacc = 0.f;
#pragma unroll
    for (int r = 0; r < 4; r++) {
        const int row = rbase + r;
        float w0 = W[(size_t)row * 30 + l15];
        float w1 = c2ok ? W[(size_t)row * 30 + 16 + l15] : -1e30f;
        float m = fmaxf(w0, w1);
#pragma unroll
        for (int mm = 1; mm < 16; mm <<= 1) m = fmaxf(m, __shfl_xor(m, mm, 64));
        float e0 = __expf(w0 - m);
        float e1 = c2ok ? __expf(w1 - m) : 0.f;
        float s = e0 + e1;
#pragma unroll
        for (int mm = 1; mm < 16; mm <<= 1) s += __shfl_xor(s, mm, 64);
        float inv = 1.0f / s;
        float p0 = e0 * inv, p1 = e1 * inv;
        float Sn = S[row], Sn2 = Sn * Sn;
        float F0 = -0.5f * (acc[0][r] - 2.0f * Sn * acc[2][r] + Sn2 * d0);
        float F1 = -0.5f * (acc[1][r] - 2.0f * Sn * acc[3][r] + Sn2 * d1);
        float lp = p0 * F0 + (c2ok ? p1 * F1 : 0.f);
#pragma unroll
        for (int mm = 1; mm < 16; mm <<= 1) lp += __shfl_xor(lp, mm, 64);
        llacc += lp;

        out[2 + (size_t)row * 30 + l15] = p0;
        float lg0 = __logf(p0 + 1e-8f);
        Pb[(size_t)row * 32 + l15] = (unsigned short)f2bf_u(p0);
        Lb[(size_t)row * 32 + l15] = (unsigned short)f2bf_u(lg0);
        if (c2ok) {
            out[2 + (size_t)row * 30 + 16 + l15] = p1;
            float lg1 = __logf(p1 + 1e-8f);
            Pb[(size_t)row * 32 + 16 + l15] = (unsigned short)f2bf_u(p1);
            Lb[(size_t)row * 32 + 16 + l15] = (unsigned short)f2bf_u(lg1);
        } else {
            Pb[(size_t)row * 32 + 16 + l15] = 0;
            Lb[(size_t)row * 32 + 16 + l15] = 0;
        }
        if (l15 >= 14)                xl[(size_t)row * 8 + (l15 - 14)] = acc[3][r] + bl[l15 - 14];
        else if (l15 < 6)             xl[(size_t)row * 8 + (l15 + 2)]  = acc[4][r] + bl[l15 + 2];
        if (l15 >= 6 && l15 < 14)     xr[(size_t)row * 8 + (l15 - 6)]  = acc[4][r] + br[l15 - 6];
    }
    llacc += __shfl_xor(llacc, 16, 64);
    llacc += __shfl_xor(llacc, 32, 64);
    if (l == 0) atomicAdd(&out[0], llacc * (1.0f / N_CELLS));
}

// ---------------------------------------------------------------------------
// K2: SINGLE edge pass, 4 lanes/edge (coalesced gathers), (p, p*dot) pair
// atomics into NREP replicated same-line slots by dst.
// ---------------------------------------------------------------------------
__global__ __launch_bounds__(256) void edge_pass(
    const int* __restrict__ ei, const float* __restrict__ xl,
    const float* __restrict__ xr, const float* __restrict__ att,
    const unsigned short* __restrict__ Pb, const unsigned short* __restrict__ Lb,
    float* __restrict__ dn4) {
    const int t = threadIdx.x;
    const int g = t >> 2;                     // group in block [0,64)
    const int j = t & 3;
    const int e = blockIdx.x * 64 + g;        // E = 12500*64 exactly
    const int src = ei[e];
    const int dst = ei[E_EDGES + e];

    float2 lv = *(const float2*)&xl[(size_t)src * 8 + j * 2];
    float2 rv = *(const float2*)&xr[(size_t)dst * 8 + j * 2];
    float2 av = *(const float2*)&att[j * 2];
    float ev = lrelu02(lv.x + rv.x) * av.x + lrelu02(lv.y + rv.y) * av.y;
    ev += __shfl_xor(ev, 1, 64);
    ev += __shfl_xor(ev, 2, 64);
    float p = __expf(ev);                     // |ev| ~ O(10): no max-subtraction

    int4 a = *(const int4*)&Pb[(size_t)src * 32 + j * 8];
    int4 b = *(const int4*)&Lb[(size_t)dst * 32 + j * 8];
    float dot = dp4(a, b);
    dot += __shfl_xor(dot, 1, 64);
    dot += __shfl_xor(dot, 2, 64);

    float* base = &dn4[((size_t)(blockIdx.x & (NREP - 1)) * N_CELLS + dst) * 2];
    if (j == 0)      atomicAdd(base, p);
    else if (j == 1) atomicAdd(base + 1, p * dot);
}

// ---------------------------------------------------------------------------
// K3: finalize — fold replicas, ce = -sum numer/denom / N
// ---------------------------------------------------------------------------
__global__ __launch_bounds__(256) void finalize_kernel(const float* __restrict__ dn4,
                                                       float* __restrict__ out) {
    const int t = threadIdx.x;
    const int i = blockIdx.x * 256 + t;
    float c = 0.f;
    if (i < N_CELLS) {
        float d  = (dn4[(size_t)i * 2]     + dn4[((size_t)N_CELLS + i) * 2]) +
                   (dn4[((size_t)2 * N_CELLS + i) * 2] + dn4[((size_t)3 * N_CELLS + i) * 2]);
        float nm = (dn4[(size_t)i * 2 + 1] + dn4[((size_t)N_CELLS + i) * 2 + 1]) +
                   (dn4[((size_t)2 * N_CELLS + i) * 2 + 1] + dn4[((size_t)3 * N_CELLS + i) * 2 + 1]);
        c = nm / (d + 1e-16f);
    }
#pragma unroll
    for (int m = 1; m < 64; m <<= 1) c += __shfl_xor(c, m, 64);
    __shared__ float wsum[4];
    if ((t & 63) == 0) wsum[t >> 6] = c;
    __syncthreads();
    if (t == 0)
        atomicAdd(&out[1], -(wsum[0] + wsum[1] + wsum[2] + wsum[3]) * (1.0f / N_CELLS));
}

// ---------------------------------------------------------------------------
// launch
// ---------------------------------------------------------------------------
extern "C" void kernel_launch(void* const* d_in, const int* in_sizes, int n_in,
                              void* d_out, int out_size, void* d_ws, size_t ws_size,
                              hipStream_t stream) {
    const float* X   = (const float*)d_in[0];
    const float* Mu  = (const float*)d_in[1];
    const float* Var = (const float*)d_in[2];
    const int*   ei  = (const int*)d_in[3];
    const float* W   = (const float*)d_in[4];
    const float* S   = (const float*)d_in[5];
    const float* Wl  = (const float*)d_in[6];
    const float* bl  = (const float*)d_in[7];
    const float* Wr  = (const float*)d_in[8];
    const float* br  = (const float*)d_in[9];
    const float* att = (const float*)d_in[10];

    float* out = (float*)d_out;

    // ws layout (float offsets)
    float* wsf = (float*)d_ws;
    unsigned short* CoefB  = (unsigned short*)wsf;             // 80*1024 us = 40960 fl
    float* Dvec            = wsf + 40960;                      // 32
    unsigned short* Pb     = (unsigned short*)(wsf + 40992);   // N*32 us = 800000 fl
    unsigned short* Lb     = (unsigned short*)(wsf + 840992);  // N*32 us
    float* xl              = wsf + 1640992;                    // N*8
    float* xr              = wsf + 2040992;                    // N*8
    float* dn4             = wsf + 2440992;                    // NREP*N*2 = 400000

    prep_kernel<<<80, 256, 0, stream>>>(Mu, Var, Wl, Wr, CoefB, Dvec, dn4, out);
    main_rows_kernel<<<(N_CELLS + 31) / 32, 128, 0, stream>>>(
        X, W, S, bl, br, CoefB, Dvec, out, Pb, Lb, xl, xr);
    edge_pass<<<E_EDGES / 64, 256, 0, stream>>>(ei, xl, xr, att, Pb, Lb, dn4);
    finalize_kernel<<<(N_CELLS + 255) / 256, 256, 0, stream>>>(dn4, out);
}